// Round 2
// baseline (1331.623 us; speedup 1.0000x reference)
//
#include <hip/hip_runtime.h>
#include <math.h>

// ---- problem constants ----
#define N_NODES 250000
#define F_DIM   134
#define H_DIM   128
#define K_POOL  4
#define D_EMB   128
#define B_GR    256
#define EPSF    1e-16f
#define OUT_W   (K_POOL * D_EMB + 7)   // 519

// ---- tiling ----
#define BM   128
#define KC   32
#define XPAD 5      // stride 133 (odd) -> conflict-free x_s staging writes
#define GMAX 16

// ---- workspace layout (bytes) ----
#define OFF_SCORES 0                                   // N*4 f32 = 4,000,000 B
#define OFF_SEG    (N_NODES * 4 * 4)                   // (B+1) int
#define OFF_MAX    (OFF_SEG + 2048)                    // 256*4 f32
#define OFF_DEN    (OFF_MAX + 4096)                    // 256*4 f32
#define OFF_POOL   (OFF_DEN + 4096)                    // 256*4*128 f32

// K0: segment offsets via binary search on sorted batch
__global__ void seg_kernel(const int* __restrict__ batch, int* __restrict__ seg) {
    int b = blockIdx.x * blockDim.x + threadIdx.x;
    if (b > B_GR) return;
    int lo = 0, hi = N_NODES;
    while (lo < hi) {
        int mid = (lo + hi) >> 1;
        if (batch[mid] < b) lo = mid + 1; else hi = mid;
    }
    seg[b] = lo;   // first index with batch[i] >= b ; seg[256] = N
}

// K1: gate path GEMM + fused score reduce -> scores[N][4]
__launch_bounds__(256)
__global__ void gate_kernel(const float* __restrict__ x,
                            const float* __restrict__ w1,   // [4][134][128]
                            const float* __restrict__ b1,   // [4][128]
                            const float* __restrict__ w2,   // [4][128]
                            const float* __restrict__ b2,   // [4]
                            float* __restrict__ scores)     // [N][4]
{
    const int k  = blockIdx.y;
    const int m0 = blockIdx.x * BM;
    const int t  = threadIdx.x;
    const int ty = t >> 4, tx = t & 15;

    __shared__ float x_s[KC][BM + XPAD];
    __shared__ float w_s[KC][H_DIM];

    float acc[8][8];
#pragma unroll
    for (int i = 0; i < 8; ++i)
#pragma unroll
        for (int j = 0; j < 8; ++j) acc[i][j] = 0.f;

    const float* wk = w1 + k * (F_DIM * H_DIM);

    for (int kbeg = 0; kbeg < F_DIM; kbeg += KC) {
        const int klen = (F_DIM - kbeg) < KC ? (F_DIM - kbeg) : KC;
        __syncthreads();
        {   // stage x^T : x_s[f][m]
            const int f  = t & 31;
            const int mb = t >> 5;
            const bool fok = (f < klen);
#pragma unroll
            for (int j = 0; j < 16; ++j) {
                const int m  = mb + (j << 3);
                const int gm = m0 + m;
                float v = 0.f;
                if (fok && gm < N_NODES) v = x[gm * F_DIM + kbeg + f];
                x_s[f][m] = v;
            }
        }
        {   // stage W : w_s[f][h]
#pragma unroll
            for (int j = 0; j < 4; ++j) {
                const int q  = t + (j << 8);
                const int f  = q >> 5;
                const int h4 = (q & 31) << 2;
                float4 v = make_float4(0.f, 0.f, 0.f, 0.f);
                if (f < klen) v = *(const float4*)(wk + (kbeg + f) * H_DIM + h4);
                *(float4*)&w_s[f][h4] = v;
            }
        }
        __syncthreads();
        for (int f = 0; f < klen; ++f) {
            float xv[8], wv[8];
            *(float4*)&xv[0] = *(const float4*)&x_s[f][ty * 8];
            *(float4*)&xv[4] = *(const float4*)&x_s[f][ty * 8 + 4];
            *(float4*)&wv[0] = *(const float4*)&w_s[f][tx * 8];
            *(float4*)&wv[4] = *(const float4*)&w_s[f][tx * 8 + 4];
#pragma unroll
            for (int i = 0; i < 8; ++i)
#pragma unroll
                for (int j = 0; j < 8; ++j)
                    acc[i][j] = fmaf(xv[i], wv[j], acc[i][j]);
        }
    }

    // epilogue: relu(+b1), dot w2, reduce over tx, +b2
    float b1v[8], w2v[8];
    *(float4*)&b1v[0] = *(const float4*)(b1 + k * H_DIM + tx * 8);
    *(float4*)&b1v[4] = *(const float4*)(b1 + k * H_DIM + tx * 8 + 4);
    *(float4*)&w2v[0] = *(const float4*)(w2 + k * H_DIM + tx * 8);
    *(float4*)&w2v[4] = *(const float4*)(w2 + k * H_DIM + tx * 8 + 4);
    const float b2v = b2[k];

#pragma unroll
    for (int i = 0; i < 8; ++i) {
        float s = 0.f;
#pragma unroll
        for (int j = 0; j < 8; ++j) {
            float g1 = fmaxf(acc[i][j] + b1v[j], 0.f);
            s = fmaf(g1, w2v[j], s);
        }
        s += __shfl_xor(s, 1);
        s += __shfl_xor(s, 2);
        s += __shfl_xor(s, 4);
        s += __shfl_xor(s, 8);
        if (tx == 0) {
            const int m = m0 + ty * 8 + i;
            if (m < N_NODES) scores[m * 4 + k] = s + b2v;
        }
    }
}

// K2: per-graph segmented softmax stats; also zero pooled accumulator
__launch_bounds__(256)
__global__ void stats_kernel(const float* __restrict__ scores,
                             const int* __restrict__ seg,
                             float* __restrict__ maxv,
                             float* __restrict__ denom,
                             float* __restrict__ pooled)
{
    const int g = blockIdx.x;
    const int t = threadIdx.x;
    const int s = seg[g], e = seg[g + 1];
    const float4* sc4 = (const float4*)scores;

    float mx[4] = {-INFINITY, -INFINITY, -INFINITY, -INFINITY};
    for (int n = s + t; n < e; n += 256) {
        float4 v = sc4[n];
        mx[0] = fmaxf(mx[0], v.x); mx[1] = fmaxf(mx[1], v.y);
        mx[2] = fmaxf(mx[2], v.z); mx[3] = fmaxf(mx[3], v.w);
    }
#pragma unroll
    for (int c = 0; c < 4; ++c)
        for (int off = 32; off; off >>= 1)
            mx[c] = fmaxf(mx[c], __shfl_down(mx[c], off));

    __shared__ float redbuf[4][4];
    __shared__ float bmax[4];
    const int wid = t >> 6, lane = t & 63;
    if (lane == 0) {
#pragma unroll
        for (int c = 0; c < 4; ++c) redbuf[wid][c] = mx[c];
    }
    __syncthreads();
    if (t == 0) {
#pragma unroll
        for (int c = 0; c < 4; ++c) {
            float m = redbuf[0][c];
            m = fmaxf(m, redbuf[1][c]); m = fmaxf(m, redbuf[2][c]); m = fmaxf(m, redbuf[3][c]);
            bmax[c] = m;
        }
    }
    __syncthreads();
    const float m0v = bmax[0], m1v = bmax[1], m2v = bmax[2], m3v = bmax[3];

    float sm[4] = {0.f, 0.f, 0.f, 0.f};
    for (int n = s + t; n < e; n += 256) {
        float4 v = sc4[n];
        sm[0] += expf(v.x - m0v); sm[1] += expf(v.y - m1v);
        sm[2] += expf(v.z - m2v); sm[3] += expf(v.w - m3v);
    }
#pragma unroll
    for (int c = 0; c < 4; ++c)
        for (int off = 32; off; off >>= 1)
            sm[c] += __shfl_down(sm[c], off);
    __syncthreads();
    if (lane == 0) {
#pragma unroll
        for (int c = 0; c < 4; ++c) redbuf[wid][c] = sm[c];
    }
    __syncthreads();
    if (t == 0) {
#pragma unroll
        for (int c = 0; c < 4; ++c) {
            float tot = redbuf[0][c] + redbuf[1][c] + redbuf[2][c] + redbuf[3][c];
            maxv[g * 4 + c]  = bmax[c];
            denom[g * 4 + c] = tot + EPSF;
        }
    }
    // zero pooled accumulator [g][4][128]
    pooled[g * 512 + t]       = 0.f;
    pooled[g * 512 + 256 + t] = 0.f;
}

// K3: nn path GEMM + gated per-graph accumulation -> pooled[B][4][128]
__launch_bounds__(256)
__global__ void pool_kernel(const float* __restrict__ x,
                            const int* __restrict__ batch,
                            const float* __restrict__ w1,   // nn_w1 [4][134][128]
                            const float* __restrict__ b1,   // nn_b1 [4][128]
                            const float* __restrict__ scores,
                            const float* __restrict__ maxv,
                            const float* __restrict__ denom,
                            float* __restrict__ pooled)
{
    const int k  = blockIdx.y;
    const int m0 = blockIdx.x * BM;
    const int t  = threadIdx.x;
    const int ty = t >> 4, tx = t & 15;

    __shared__ float x_s[KC][BM + XPAD];
    __shared__ float w_s[KC][H_DIM];
    __shared__ float lds_pool[GMAX][H_DIM];

    // zero per-graph LDS accumulator (synced by the first stage sync)
#pragma unroll
    for (int j = 0; j < (GMAX * H_DIM) / 256; ++j)
        ((float*)lds_pool)[j * 256 + t] = 0.f;

    float acc[8][8];
#pragma unroll
    for (int i = 0; i < 8; ++i)
#pragma unroll
        for (int j = 0; j < 8; ++j) acc[i][j] = 0.f;

    const float* wk = w1 + k * (F_DIM * H_DIM);

    for (int kbeg = 0; kbeg < F_DIM; kbeg += KC) {
        const int klen = (F_DIM - kbeg) < KC ? (F_DIM - kbeg) : KC;
        __syncthreads();
        {
            const int f  = t & 31;
            const int mb = t >> 5;
            const bool fok = (f < klen);
#pragma unroll
            for (int j = 0; j < 16; ++j) {
                const int m  = mb + (j << 3);
                const int gm = m0 + m;
                float v = 0.f;
                if (fok && gm < N_NODES) v = x[gm * F_DIM + kbeg + f];
                x_s[f][m] = v;
            }
        }
        {
#pragma unroll
            for (int j = 0; j < 4; ++j) {
                const int q  = t + (j << 8);
                const int f  = q >> 5;
                const int h4 = (q & 31) << 2;
                float4 v = make_float4(0.f, 0.f, 0.f, 0.f);
                if (f < klen) v = *(const float4*)(wk + (kbeg + f) * H_DIM + h4);
                *(float4*)&w_s[f][h4] = v;
            }
        }
        __syncthreads();
        for (int f = 0; f < klen; ++f) {
            float xv[8], wv[8];
            *(float4*)&xv[0] = *(const float4*)&x_s[f][ty * 8];
            *(float4*)&xv[4] = *(const float4*)&x_s[f][ty * 8 + 4];
            *(float4*)&wv[0] = *(const float4*)&w_s[f][tx * 8];
            *(float4*)&wv[4] = *(const float4*)&w_s[f][tx * 8 + 4];
#pragma unroll
            for (int i = 0; i < 8; ++i)
#pragma unroll
                for (int j = 0; j < 8; ++j)
                    acc[i][j] = fmaf(xv[i], wv[j], acc[i][j]);
        }
    }

    const int g_first = batch[m0];

    float b1v[8];
    *(float4*)&b1v[0] = *(const float4*)(b1 + k * H_DIM + tx * 8);
    *(float4*)&b1v[4] = *(const float4*)(b1 + k * H_DIM + tx * 8 + 4);

    float part[8] = {0.f, 0.f, 0.f, 0.f, 0.f, 0.f, 0.f, 0.f};
    int curg = -1;

#pragma unroll
    for (int i = 0; i < 8; ++i) {
        const int m = m0 + ty * 8 + i;
        float gate = 0.f;
        int g = curg;
        if (m < N_NODES) {
            g = batch[m];
            const float sc = scores[m * 4 + k];
            gate = expf(sc - maxv[g * 4 + k]) / denom[g * 4 + k];
        }
        if (g != curg) {
            if (curg >= 0) {
                const int lg = curg - g_first;
                if (lg < GMAX) {
#pragma unroll
                    for (int j = 0; j < 8; ++j)
                        if (part[j] != 0.f) atomicAdd(&lds_pool[lg][tx * 8 + j], part[j]);
                } else {
#pragma unroll
                    for (int j = 0; j < 8; ++j)
                        if (part[j] != 0.f) atomicAdd(&pooled[(curg * K_POOL + k) * H_DIM + tx * 8 + j], part[j]);
                }
            }
#pragma unroll
            for (int j = 0; j < 8; ++j) part[j] = 0.f;
            curg = g;
        }
#pragma unroll
        for (int j = 0; j < 8; ++j) {
            const float h1 = fmaxf(acc[i][j] + b1v[j], 0.f);
            part[j] = fmaf(gate, h1, part[j]);
        }
    }
    if (curg >= 0) {
        const int lg = curg - g_first;
        if (lg < GMAX) {
#pragma unroll
            for (int j = 0; j < 8; ++j)
                if (part[j] != 0.f) atomicAdd(&lds_pool[lg][tx * 8 + j], part[j]);
        } else {
#pragma unroll
            for (int j = 0; j < 8; ++j)
                if (part[j] != 0.f) atomicAdd(&pooled[(curg * K_POOL + k) * H_DIM + tx * 8 + j], part[j]);
        }
    }

    __syncthreads();
    {
        const int mlast  = (m0 + BM - 1) < (N_NODES - 1) ? (m0 + BM - 1) : (N_NODES - 1);
        const int g_last = batch[mlast];
        int span = g_last - g_first + 1;
        if (span > GMAX) span = GMAX;
        for (int idx = t; idx < span * H_DIM; idx += 256) {
            const float v = ((const float*)lds_pool)[idx];
            if (v != 0.f) {
                const int lg = idx >> 7, c = idx & 127;
                atomicAdd(&pooled[((g_first + lg) * K_POOL + k) * H_DIM + c], v);
            }
        }
    }
}

// K4: epilogue: out[g] = [ (pooled@nn_w2 + gs*nn_b2).flatten() | 7 scalars ]
__launch_bounds__(128)
__global__ void out_kernel(const float* __restrict__ pooled,
                           const float* __restrict__ w2,   // nn_w2 [4][128][128]
                           const float* __restrict__ b2,   // nn_b2 [4][128]
                           const float* __restrict__ denom,
                           const float* __restrict__ s0, const float* __restrict__ s1,
                           const float* __restrict__ s2, const float* __restrict__ s3,
                           const float* __restrict__ s4, const float* __restrict__ s5,
                           const float* __restrict__ s6,
                           float* __restrict__ out)
{
    const int g = blockIdx.x;
    const int t = threadIdx.x;   // 0..127
    __shared__ float ps[H_DIM];
    float* orow = out + g * OUT_W;

    for (int k = 0; k < K_POOL; ++k) {
        __syncthreads();
        ps[t] = pooled[(g * K_POOL + k) * H_DIM + t];
        __syncthreads();
        const float den = denom[g * 4 + k];
        const float gs  = (den - EPSF) / den;   // segment-sum of gate (handles empty graphs)
        float a = b2[k * H_DIM + t] * gs;
        const float* wkt = w2 + (k * H_DIM) * D_EMB + t;
#pragma unroll 4
        for (int h = 0; h < H_DIM; ++h)
            a = fmaf(ps[h], wkt[h * D_EMB], a);
        orow[k * D_EMB + t] = a;
    }
    if (t < 7) {
        const float* sp;
        switch (t) {
            case 0: sp = s0; break; case 1: sp = s1; break; case 2: sp = s2; break;
            case 3: sp = s3; break; case 4: sp = s4; break; case 5: sp = s5; break;
            default: sp = s6; break;
        }
        orow[K_POOL * D_EMB + t] = sp[g];
    }
}

extern "C" void kernel_launch(void* const* d_in, const int* in_sizes, int n_in,
                              void* d_out, int out_size, void* d_ws, size_t ws_size,
                              hipStream_t stream) {
    const float* x     = (const float*)d_in[0];
    const int*   batch = (const int*)d_in[1];
    const float* n_nodes = (const float*)d_in[2];
    const float* Omegas  = (const float*)d_in[3];
    const float* Phis    = (const float*)d_in[4];
    const float* Lambdas = (const float*)d_in[5];
    const float* Omn     = (const float*)d_in[6];
    const float* Phn     = (const float*)d_in[7];
    const float* Lan     = (const float*)d_in[8];
    const float* gw1 = (const float*)d_in[9];
    const float* gb1 = (const float*)d_in[10];
    const float* gw2 = (const float*)d_in[11];
    const float* gb2 = (const float*)d_in[12];
    const float* nw1 = (const float*)d_in[13];
    const float* nb1 = (const float*)d_in[14];
    const float* nw2 = (const float*)d_in[15];
    const float* nb2 = (const float*)d_in[16];

    char* ws = (char*)d_ws;
    float* scores = (float*)(ws + OFF_SCORES);
    int*   seg    = (int*)(ws + OFF_SEG);
    float* maxv   = (float*)(ws + OFF_MAX);
    float* denom  = (float*)(ws + OFF_DEN);
    float* pooled = (float*)(ws + OFF_POOL);
    float* out    = (float*)d_out;

    seg_kernel<<<2, 256, 0, stream>>>(batch, seg);

    dim3 gemm_grid((N_NODES + BM - 1) / BM, K_POOL);
    gate_kernel<<<gemm_grid, 256, 0, stream>>>(x, gw1, gb1, gw2, gb2, scores);
    stats_kernel<<<B_GR, 256, 0, stream>>>(scores, seg, maxv, denom, pooled);
    pool_kernel<<<gemm_grid, 256, 0, stream>>>(x, batch, nw1, nb1, scores, maxv, denom, pooled);
    out_kernel<<<B_GR, 128, 0, stream>>>(pooled, nw2, nb2, denom,
                                         n_nodes, Omegas, Phis, Lambdas, Omn, Phn, Lan, out);
}

// Round 4
// 743.658 us; speedup vs baseline: 1.7906x; 1.7906x over previous
//
#include <hip/hip_runtime.h>
#include <math.h>

// ---- problem constants ----
#define N_NODES 250000
#define F_DIM   134
#define H_DIM   128
#define K_POOL  4
#define B_GR    256
#define EPSF    1e-16f
#define OUT_W   (K_POOL * H_DIM + 7)   // 519

// ---- tiling ----
#define BM      128
#define BK      32
#define KP      160                         // padded K (5 * 32)
#define KSTEPS  5
#define GMAX    16
#define NBLK    ((N_NODES + BM - 1) / BM)   // 1954
#define N_PAD   (NBLK * BM)                 // 250112 (zero-padded rows)

// ---- workspace layout (bytes) ----
#define SZ_X       (N_PAD * KP * 2)                    // 80,035,840
#define SZ_W       (K_POOL * H_DIM * KP * 2)           // 163,840
#define OFF_XH     0
#define OFF_XL     (OFF_XH + SZ_X)
#define OFF_WHG    (OFF_XL + SZ_X)
#define OFF_WLG    (OFF_WHG + SZ_W)
#define OFF_WHN    (OFF_WLG + SZ_W)
#define OFF_WLN    (OFF_WHN + SZ_W)
#define OFF_SCORES (OFF_WLN + SZ_W)
#define OFF_SEG    (OFF_SCORES + N_NODES * 16)
#define OFF_MAX    (OFF_SEG + 2048)
#define OFF_DEN    (OFF_MAX + 4096)
#define OFF_POOL   (OFF_DEN + 4096)

typedef __attribute__((ext_vector_type(8))) short bf16x8;
typedef __attribute__((ext_vector_type(4))) float f32x4;

__device__ __forceinline__ ushort f2bf(float f) {
    union { float f; unsigned u; } v; v.f = f;
    const unsigned u = v.u;
    return (ushort)((u + 0x7FFFu + ((u >> 16) & 1u)) >> 16);   // RTNE
}
__device__ __forceinline__ float bf2f(ushort h) {
    union { unsigned u; float f; } v; v.u = ((unsigned)h) << 16; return v.f;
}
// XOR swizzle: conflict-free ds_read_b128 of [128 rows][32 k] bf16 tiles
__device__ __forceinline__ int swz(int row, int kg) {
    return ((row << 6) + (kg << 4)) ^ ((row & 7) << 4);   // byte offset, 16B units
}

// ---- P0: x -> hi/lo bf16, padded [N_PAD][KP] ----
__launch_bounds__(256)
__global__ void cvt_x_kernel(const float* __restrict__ x,
                             ushort* __restrict__ xh, ushort* __restrict__ xl)
{
    const int idx = (blockIdx.x * 256 + threadIdx.x) * 4;   // over N_PAD*KP
    if (idx >= N_PAD * KP) return;
    const int row = idx / KP;
    const int col = idx - row * KP;
    float v[4] = {0.f, 0.f, 0.f, 0.f};
    if (row < N_NODES) {
        const float* xr = x + row * F_DIM + col;
        if (col + 4 <= F_DIM) {
            float2 a = *(const float2*)(xr);
            float2 b = *(const float2*)(xr + 2);
            v[0] = a.x; v[1] = a.y; v[2] = b.x; v[3] = b.y;
        } else if (col < F_DIM) {   // col == 132
            float2 a = *(const float2*)(xr);
            v[0] = a.x; v[1] = a.y;
        }
    }
    ushort4 h, l;
    h.x = f2bf(v[0]); l.x = f2bf(v[0] - bf2f(h.x));
    h.y = f2bf(v[1]); l.y = f2bf(v[1] - bf2f(h.y));
    h.z = f2bf(v[2]); l.z = f2bf(v[2] - bf2f(h.z));
    h.w = f2bf(v[3]); l.w = f2bf(v[3] - bf2f(h.w));
    *(ushort4*)(xh + idx) = h;
    *(ushort4*)(xl + idx) = l;
}

// ---- P1: w1 [4][134][128] -> transposed hi/lo [4][128][KP] ----
__launch_bounds__(256)
__global__ void cvt_w_kernel(const float* __restrict__ wg, const float* __restrict__ wn,
                             ushort* __restrict__ whg, ushort* __restrict__ wlg,
                             ushort* __restrict__ whn, ushort* __restrict__ wln)
{
    const int idx = blockIdx.x * 256 + threadIdx.x;   // over K_POOL*H_DIM*KP
    if (idx >= K_POOL * H_DIM * KP) return;
    const int k   = idx % KP;
    const int pc  = idx / KP;
    const int col = pc & 127, p = pc >> 7;
    const float* src = blockIdx.y ? wn : wg;
    const float v = (k < F_DIM) ? src[(p * F_DIM + k) * H_DIM + col] : 0.f;
    const ushort h = f2bf(v);
    const ushort lo = f2bf(v - bf2f(h));
    if (blockIdx.y) { whn[idx] = h; wln[idx] = lo; }
    else            { whg[idx] = h; wlg[idx] = lo; }
}

// ---- GEMM staging: pure bf16 copy, swizzled ----
__device__ __forceinline__ void mm_stage(const ushort* __restrict__ Ahs,
                                         const ushort* __restrict__ Als,
                                         const ushort* __restrict__ Bhs,
                                         const ushort* __restrict__ Bls,
                                         int kbeg, int t,
                                         short* Ah, short* Al, short* Bh, short* Bl)
{
    const int row  = t >> 1;         // A row / B col
    const int half = t & 1;
    const int base = row * KP + kbeg + half * 16;
    const int off0 = swz(row, half * 2) >> 1;
    const int off1 = swz(row, half * 2 + 1) >> 1;
    *(bf16x8*)(Ah + off0) = *(const bf16x8*)(Ahs + base);
    *(bf16x8*)(Ah + off1) = *(const bf16x8*)(Ahs + base + 8);
    *(bf16x8*)(Al + off0) = *(const bf16x8*)(Als + base);
    *(bf16x8*)(Al + off1) = *(const bf16x8*)(Als + base + 8);
    *(bf16x8*)(Bh + off0) = *(const bf16x8*)(Bhs + base);
    *(bf16x8*)(Bh + off1) = *(const bf16x8*)(Bhs + base + 8);
    *(bf16x8*)(Bl + off0) = *(const bf16x8*)(Bls + base);
    *(bf16x8*)(Bl + off1) = *(const bf16x8*)(Bls + base + 8);
}

// one K-step of MFMAs: wave wv covers rows wv*32..+31, all 128 cols
__device__ __forceinline__ void mm_compute(int t, const short* Ah, const short* Al,
                                           const short* Bh, const short* Bl,
                                           f32x4 acc[2][8])
{
    const int lane = t & 63, wv = t >> 6;
    bf16x8 ah[2], al[2];
#pragma unroll
    for (int r = 0; r < 2; ++r) {
        const int rowA = wv * 32 + r * 16 + (lane & 15);
        const int off  = swz(rowA, lane >> 4) >> 1;
        ah[r] = *(const bf16x8*)(Ah + off);
        al[r] = *(const bf16x8*)(Al + off);
    }
#pragma unroll
    for (int c = 0; c < 8; ++c) {
        const int rowB = c * 16 + (lane & 15);
        const int off  = swz(rowB, lane >> 4) >> 1;
        const bf16x8 bh = *(const bf16x8*)(Bh + off);
        const bf16x8 bl = *(const bf16x8*)(Bl + off);
#pragma unroll
        for (int r = 0; r < 2; ++r) {
            acc[r][c] = __builtin_amdgcn_mfma_f32_16x16x32_bf16(ah[r], bh, acc[r][c], 0, 0, 0);
            acc[r][c] = __builtin_amdgcn_mfma_f32_16x16x32_bf16(ah[r], bl, acc[r][c], 0, 0, 0);
            acc[r][c] = __builtin_amdgcn_mfma_f32_16x16x32_bf16(al[r], bh, acc[r][c], 0, 0, 0);
        }
    }
}

// K0: segment offsets
__global__ void seg_kernel(const int* __restrict__ batch, int* __restrict__ seg) {
    int b = blockIdx.x * blockDim.x + threadIdx.x;
    if (b > B_GR) return;
    int lo = 0, hi = N_NODES;
    while (lo < hi) {
        int mid = (lo + hi) >> 1;
        if (batch[mid] < b) lo = mid + 1; else hi = mid;
    }
    seg[b] = lo;
}

// K1: gate GEMM (MFMA) + fused score reduce -> scores[N][4]
__launch_bounds__(256, 2)
__global__ void gate_kernel(const ushort* __restrict__ xh, const ushort* __restrict__ xl,
                            const ushort* __restrict__ wh, const ushort* __restrict__ wl,
                            const float* __restrict__ b1,
                            const float* __restrict__ w2,
                            const float* __restrict__ b2,
                            float* __restrict__ scores)
{
    __shared__ short Ah[4096], Al[4096], Bh[4096], Bl[4096];
    const int k = blockIdx.y, m0 = blockIdx.x * BM, t = threadIdx.x;
    const ushort* Ahs = xh + (long)m0 * KP;
    const ushort* Als = xl + (long)m0 * KP;
    const ushort* Bhs = wh + k * H_DIM * KP;
    const ushort* Bls = wl + k * H_DIM * KP;

    f32x4 acc[2][8];
    const f32x4 z = {0.f, 0.f, 0.f, 0.f};
#pragma unroll
    for (int r = 0; r < 2; ++r)
#pragma unroll
        for (int c = 0; c < 8; ++c) acc[r][c] = z;

    for (int ks = 0; ks < KSTEPS; ++ks) {
        __syncthreads();
        mm_stage(Ahs, Als, Bhs, Bls, ks * BK, t, Ah, Al, Bh, Bl);
        __syncthreads();
        mm_compute(t, Ah, Al, Bh, Bl, acc);
    }

    const int lane = t & 63, wv = t >> 6;
    float b1v[8], w2v[8];
#pragma unroll
    for (int c = 0; c < 8; ++c) {
        const int col = c * 16 + (lane & 15);
        b1v[c] = b1[k * H_DIM + col];
        w2v[c] = w2[k * H_DIM + col];
    }
    const float b2v = b2[k];
#pragma unroll
    for (int r = 0; r < 2; ++r)
#pragma unroll
        for (int q = 0; q < 4; ++q) {
            float s = 0.f;
#pragma unroll
            for (int c = 0; c < 8; ++c)
                s = fmaf(fmaxf(acc[r][c][q] + b1v[c], 0.f), w2v[c], s);
            s += __shfl_xor(s, 1); s += __shfl_xor(s, 2);
            s += __shfl_xor(s, 4); s += __shfl_xor(s, 8);
            if ((lane & 15) == 0) {
                const int m = m0 + wv * 32 + r * 16 + (lane >> 4) * 4 + q;
                if (m < N_NODES) scores[m * 4 + k] = s + b2v;
            }
        }
}

// K2: per-graph softmax stats + zero pooled
__launch_bounds__(256)
__global__ void stats_kernel(const float* __restrict__ scores,
                             const int* __restrict__ seg,
                             float* __restrict__ maxv,
                             float* __restrict__ denom,
                             float* __restrict__ pooled)
{
    const int g = blockIdx.x;
    const int t = threadIdx.x;
    const int s = seg[g], e = seg[g + 1];
    const float4* sc4 = (const float4*)scores;

    float mx[4] = {-INFINITY, -INFINITY, -INFINITY, -INFINITY};
    for (int n = s + t; n < e; n += 256) {
        float4 v = sc4[n];
        mx[0] = fmaxf(mx[0], v.x); mx[1] = fmaxf(mx[1], v.y);
        mx[2] = fmaxf(mx[2], v.z); mx[3] = fmaxf(mx[3], v.w);
    }
#pragma unroll
    for (int c = 0; c < 4; ++c)
        for (int off = 32; off; off >>= 1)
            mx[c] = fmaxf(mx[c], __shfl_down(mx[c], off));

    __shared__ float redbuf[4][4];
    __shared__ float bmax[4];
    const int wid = t >> 6, lane = t & 63;
    if (lane == 0)
#pragma unroll
        for (int c = 0; c < 4; ++c) redbuf[wid][c] = mx[c];
    __syncthreads();
    if (t == 0)
#pragma unroll
        for (int c = 0; c < 4; ++c) {
            float m = redbuf[0][c];
            m = fmaxf(m, redbuf[1][c]); m = fmaxf(m, redbuf[2][c]); m = fmaxf(m, redbuf[3][c]);
            bmax[c] = m;
        }
    __syncthreads();
    const float m0v = bmax[0], m1v = bmax[1], m2v = bmax[2], m3v = bmax[3];

    float sm[4] = {0.f, 0.f, 0.f, 0.f};
    for (int n = s + t; n < e; n += 256) {
        float4 v = sc4[n];
        sm[0] += expf(v.x - m0v); sm[1] += expf(v.y - m1v);
        sm[2] += expf(v.z - m2v); sm[3] += expf(v.w - m3v);
    }
#pragma unroll
    for (int c = 0; c < 4; ++c)
        for (int off = 32; off; off >>= 1)
            sm[c] += __shfl_down(sm[c], off);
    __syncthreads();
    if (lane == 0)
#pragma unroll
        for (int c = 0; c < 4; ++c) redbuf[wid][c] = sm[c];
    __syncthreads();
    if (t == 0)
#pragma unroll
        for (int c = 0; c < 4; ++c) {
            maxv[g * 4 + c]  = bmax[c];
            denom[g * 4 + c] = redbuf[0][c] + redbuf[1][c] + redbuf[2][c] + redbuf[3][c] + EPSF;
        }
    pooled[g * 512 + t]       = 0.f;
    pooled[g * 512 + 256 + t] = 0.f;
}

// K3: nn GEMM (MFMA) + gated per-graph accumulation -> pooled[B][4][128]
__launch_bounds__(256, 2)
__global__ void pool_kernel(const ushort* __restrict__ xh, const ushort* __restrict__ xl,
                            const ushort* __restrict__ wh, const ushort* __restrict__ wl,
                            const int* __restrict__ batch,
                            const float* __restrict__ b1,
                            const float* __restrict__ scores,
                            const float* __restrict__ maxv,
                            const float* __restrict__ denom,
                            float* __restrict__ pooled)
{
    __shared__ short Ah[4096], Al[4096], Bh[4096], Bl[4096];
    __shared__ float lds_pool[GMAX][H_DIM];
    const int k = blockIdx.y, m0 = blockIdx.x * BM, t = threadIdx.x;
    const ushort* Ahs = xh + (long)m0 * KP;
    const ushort* Als = xl + (long)m0 * KP;
    const ushort* Bhs = wh + k * H_DIM * KP;
    const ushort* Bls = wl + k * H_DIM * KP;

    for (int idx = t; idx < GMAX * H_DIM; idx += 256)
        ((float*)lds_pool)[idx] = 0.f;

    f32x4 acc[2][8];
    const f32x4 z = {0.f, 0.f, 0.f, 0.f};
#pragma unroll
    for (int r = 0; r < 2; ++r)
#pragma unroll
        for (int c = 0; c < 8; ++c) acc[r][c] = z;

    for (int ks = 0; ks < KSTEPS; ++ks) {
        __syncthreads();
        mm_stage(Ahs, Als, Bhs, Bls, ks * BK, t, Ah, Al, Bh, Bl);
        __syncthreads();
        mm_compute(t, Ah, Al, Bh, Bl, acc);
    }

    const int lane = t & 63, wv = t >> 6;
    const int gfirst0 = batch[m0];
    float b1v[8];
#pragma unroll
    for (int c = 0; c < 8; ++c)
        b1v[c] = b1[k * H_DIM + c * 16 + (lane & 15)];

#pragma unroll
    for (int r = 0; r < 2; ++r) {
        const int mrow = m0 + wv * 32 + r * 16;
        if (mrow >= N_NODES) continue;                       // wave-uniform
        const int mhi   = (mrow + 15 < N_NODES) ? mrow + 15 : N_NODES - 1;
        const int ga    = batch[mrow];
        const bool unif = (batch[mhi] == ga) && (mrow + 15 < N_NODES);
        if (unif) {
            const float mxv = maxv[ga * 4 + k];
            const float den = denom[ga * 4 + k];
            float gates[4];
#pragma unroll
            for (int q = 0; q < 4; ++q) {
                const int m = mrow + (lane >> 4) * 4 + q;
                gates[q] = expf(scores[m * 4 + k] - mxv) / den;
            }
            const int lg = ga - gfirst0;
#pragma unroll
            for (int c = 0; c < 8; ++c) {
                float p = 0.f;
#pragma unroll
                for (int q = 0; q < 4; ++q)
                    p = fmaf(gates[q], fmaxf(acc[r][c][q] + b1v[c], 0.f), p);
                p += __shfl_xor(p, 16);
                p += __shfl_xor(p, 32);
                if (lane < 16) {
                    if (lg < GMAX) atomicAdd(&lds_pool[lg][c * 16 + lane], p);
                    else atomicAdd(&pooled[(ga * K_POOL + k) * H_DIM + c * 16 + lane], p);
                }
            }
        } else {
#pragma unroll
            for (int q = 0; q < 4; ++q) {
                const int m = mrow + (lane >> 4) * 4 + q;
                const bool val = m < N_NODES;
                int g = ga; float gate = 0.f;
                if (val) {
                    g = batch[m];
                    gate = expf(scores[m * 4 + k] - maxv[g * 4 + k]) / denom[g * 4 + k];
                }
                const int lg = g - gfirst0;
#pragma unroll
                for (int c = 0; c < 8; ++c) {
                    const float v = gate * fmaxf(acc[r][c][q] + b1v[c], 0.f);
                    if (val && v != 0.f) {
                        if (lg < GMAX) atomicAdd(&lds_pool[lg][c * 16 + (lane & 15)], v);
                        else atomicAdd(&pooled[(g * K_POOL + k) * H_DIM + c * 16 + (lane & 15)], v);
                    }
                }
            }
        }
    }

    __syncthreads();
    {
        const int mlast = (m0 + BM - 1 < N_NODES) ? m0 + BM - 1 : N_NODES - 1;
        int span = batch[mlast] - gfirst0 + 1;
        if (span > GMAX) span = GMAX;
        for (int idx = t; idx < span * H_DIM; idx += 256) {
            const float v = ((const float*)lds_pool)[idx];
            if (v != 0.f)
                atomicAdd(&pooled[((gfirst0 + (idx >> 7)) * K_POOL + k) * H_DIM + (idx & 127)], v);
        }
    }
}

// K4: out[g] = [ (pooled@nn_w2 + gs*nn_b2).flatten() | 7 scalars ]
__launch_bounds__(128)
__global__ void out_kernel(const float* __restrict__ pooled,
                           const float* __restrict__ w2,
                           const float* __restrict__ b2,
                           const float* __restrict__ denom,
                           const float* __restrict__ s0, const float* __restrict__ s1,
                           const float* __restrict__ s2, const float* __restrict__ s3,
                           const float* __restrict__ s4, const float* __restrict__ s5,
                           const float* __restrict__ s6,
                           float* __restrict__ out)
{
    const int g = blockIdx.x;
    const int t = threadIdx.x;
    __shared__ float ps[H_DIM];
    float* orow = out + g * OUT_W;

    for (int k = 0; k < K_POOL; ++k) {
        __syncthreads();
        ps[t] = pooled[(g * K_POOL + k) * H_DIM + t];
        __syncthreads();
        const float den = denom[g * 4 + k];
        const float gs  = (den - EPSF) / den;
        float a = b2[k * H_DIM + t] * gs;
        const float* wkt = w2 + (k * H_DIM) * H_DIM + t;
#pragma unroll 4
        for (int h = 0; h < H_DIM; ++h)
            a = fmaf(ps[h], wkt[h * H_DIM], a);
        orow[k * H_DIM + t] = a;
    }
    if (t < 7) {
        const float* sp;
        switch (t) {
            case 0: sp = s0; break; case 1: sp = s1; break; case 2: sp = s2; break;
            case 3: sp = s3; break; case 4: sp = s4; break; case 5: sp = s5; break;
            default: sp = s6; break;
        }
        orow[K_POOL * H_DIM + t] = sp[g];
    }
}

extern "C" void kernel_launch(void* const* d_in, const int* in_sizes, int n_in,
                              void* d_out, int out_size, void* d_ws, size_t ws_size,
                              hipStream_t stream) {
    const float* x     = (const float*)d_in[0];
    const int*   batch = (const int*)d_in[1];
    const float* n_nodes = (const float*)d_in[2];
    const float* Omegas  = (const float*)d_in[3];
    const float* Phis    = (const float*)d_in[4];
    const float* Lambdas = (const float*)d_in[5];
    const float* Omn     = (const float*)d_in[6];
    const float* Phn     = (const float*)d_in[7];
    const float* Lan     = (const float*)d_in[8];
    const float* gw1 = (const float*)d_in[9];
    const float* gb1 = (const float*)d_in[10];
    const float* gw2 = (const float*)d_in[11];
    const float* gb2 = (const float*)d_in[12];
    const float* nw1 = (const float*)d_in[13];
    const float* nb1 = (const float*)d_in[14];
    const float* nw2 = (const float*)d_in[15];
    const float* nb2 = (const float*)d_in[16];

    char* ws = (char*)d_ws;
    ushort* xh  = (ushort*)(ws + OFF_XH);
    ushort* xl  = (ushort*)(ws + OFF_XL);
    ushort* whg = (ushort*)(ws + OFF_WHG);
    ushort* wlg = (ushort*)(ws + OFF_WLG);
    ushort* whn = (ushort*)(ws + OFF_WHN);
    ushort* wln = (ushort*)(ws + OFF_WLN);
    float* scores = (float*)(ws + OFF_SCORES);
    int*   seg    = (int*)(ws + OFF_SEG);
    float* maxv   = (float*)(ws + OFF_MAX);
    float* denom  = (float*)(ws + OFF_DEN);
    float* pooled = (float*)(ws + OFF_POOL);
    float* out    = (float*)d_out;

    // precompute: bf16 hi/lo splits + seg offsets
    cvt_x_kernel<<<(N_PAD * KP / 4 + 255) / 256, 256, 0, stream>>>(x, xh, xl);
    dim3 wgrid((K_POOL * H_DIM * KP + 255) / 256, 2);
    cvt_w_kernel<<<wgrid, 256, 0, stream>>>(gw1, nw1, whg, wlg, whn, wln);
    seg_kernel<<<2, 256, 0, stream>>>(batch, seg);

    dim3 gemm_grid(NBLK, K_POOL);
    gate_kernel<<<gemm_grid, 256, 0, stream>>>(xh, xl, whg, wlg, gb1, gw2, gb2, scores);
    stats_kernel<<<B_GR, 256, 0, stream>>>(scores, seg, maxv, denom, pooled);
    pool_kernel<<<gemm_grid, 256, 0, stream>>>(xh, xl, whn, wln, batch, nb1,
                                               scores, maxv, denom, pooled);
    out_kernel<<<B_GR, 128, 0, stream>>>(pooled, nw2, nb2, denom,
                                         n_nodes, Omegas, Phis, Lambdas, Omn, Phn, Lan, out);
}

// Round 8
// 707.325 us; speedup vs baseline: 1.8826x; 1.0514x over previous
//
#include <hip/hip_runtime.h>
#include <math.h>

// ---- problem constants ----
#define N_NODES 250000
#define F_DIM   134
#define H_DIM   128
#define K_POOL  4
#define B_GR    256
#define EPSF    1e-16f
#define OUT_W   (K_POOL * H_DIM + 7)   // 519

// ---- tiling ----
#define BM      128
#define BK      32
#define KP      160                         // padded K (5 * 32)
#define KSTEPS  5
#define GMAX    4
#define NBLK    ((N_NODES + BM - 1) / BM)   // 1954
#define N_PAD   (NBLK * BM)                 // 250112 (zero-padded rows)

// ---- workspace layout (bytes) ----
#define SZ_X       (N_PAD * KP * 2)                    // 80,035,840
#define SZ_W       (K_POOL * H_DIM * KP * 2)           // 163,840
#define OFF_XH     0
#define OFF_XL     (OFF_XH + SZ_X)
#define OFF_WHG    (OFF_XL + SZ_X)
#define OFF_WLG    (OFF_WHG + SZ_W)
#define OFF_WHN    (OFF_WLG + SZ_W)
#define OFF_WLN    (OFF_WHN + SZ_W)
#define OFF_SCORES (OFF_WLN + SZ_W)
#define OFF_SEG    (OFF_SCORES + N_NODES * 16)
#define OFF_MAX    (OFF_SEG + 2048)
#define OFF_DEN    (OFF_MAX + 4096)
#define OFF_POOL   (OFF_DEN + 4096)

typedef __attribute__((ext_vector_type(8))) short bf16x8;
typedef __attribute__((ext_vector_type(4))) float f32x4;

__device__ __forceinline__ ushort f2bf(float f) {
    union { float f; unsigned u; } v; v.f = f;
    const unsigned u = v.u;
    return (ushort)((u + 0x7FFFu + ((u >> 16) & 1u)) >> 16);   // RTNE
}
__device__ __forceinline__ float bf2f(ushort h) {
    union { unsigned u; float f; } v; v.u = ((unsigned)h) << 16; return v.f;
}
// XOR swizzle: even-slot-distribution ds_read_b128 of [128 rows][32 k] bf16 tiles
__device__ __forceinline__ int swz(int row, int kg) {
    return ((row << 6) + (kg << 4)) ^ ((row & 7) << 4);   // byte offset, 16B units
}

// ---- P0: x -> hi/lo bf16, padded [N_PAD][KP] ----
__launch_bounds__(256)
__global__ void cvt_x_kernel(const float* __restrict__ x,
                             ushort* __restrict__ xh, ushort* __restrict__ xl)
{
    const int idx = (blockIdx.x * 256 + threadIdx.x) * 4;   // over N_PAD*KP
    if (idx >= N_PAD * KP) return;
    const int row = idx / KP;
    const int col = idx - row * KP;
    float v[4] = {0.f, 0.f, 0.f, 0.f};
    if (row < N_NODES) {
        const float* xr = x + row * F_DIM + col;
        if (col + 4 <= F_DIM) {
            float2 a = *(const float2*)(xr);
            float2 b = *(const float2*)(xr + 2);
            v[0] = a.x; v[1] = a.y; v[2] = b.x; v[3] = b.y;
        } else if (col < F_DIM) {   // col == 132
            float2 a = *(const float2*)(xr);
            v[0] = a.x; v[1] = a.y;
        }
    }
    ushort4 h, l;
    h.x = f2bf(v[0]); l.x = f2bf(v[0] - bf2f(h.x));
    h.y = f2bf(v[1]); l.y = f2bf(v[1] - bf2f(h.y));
    h.z = f2bf(v[2]); l.z = f2bf(v[2] - bf2f(h.z));
    h.w = f2bf(v[3]); l.w = f2bf(v[3] - bf2f(h.w));
    *(ushort4*)(xh + idx) = h;
    *(ushort4*)(xl + idx) = l;
}

// ---- P1: w1 [4][134][128] -> transposed hi/lo [4][128][KP] ----
__launch_bounds__(256)
__global__ void cvt_w_kernel(const float* __restrict__ wg, const float* __restrict__ wn,
                             ushort* __restrict__ whg, ushort* __restrict__ wlg,
                             ushort* __restrict__ whn, ushort* __restrict__ wln)
{
    const int idx = blockIdx.x * 256 + threadIdx.x;   // over K_POOL*H_DIM*KP
    if (idx >= K_POOL * H_DIM * KP) return;
    const int k   = idx % KP;
    const int pc  = idx / KP;
    const int col = pc & 127, p = pc >> 7;
    const float* src = blockIdx.y ? wn : wg;
    const float v = (k < F_DIM) ? src[(p * F_DIM + k) * H_DIM + col] : 0.f;
    const ushort h = f2bf(v);
    const ushort lo = f2bf(v - bf2f(h));
    if (blockIdx.y) { whn[idx] = h; wln[idx] = lo; }
    else            { whg[idx] = h; wlg[idx] = lo; }
}

// ---- GEMM staging: pure bf16 copy, swizzled ----
__device__ __forceinline__ void mm_stage(const ushort* __restrict__ Ahs,
                                         const ushort* __restrict__ Als,
                                         const ushort* __restrict__ Bhs,
                                         const ushort* __restrict__ Bls,
                                         int kbeg, int t,
                                         short* Ah, short* Al, short* Bh, short* Bl)
{
    const int row  = t >> 1;         // A row / B col
    const int half = t & 1;
    const int base = row * KP + kbeg + half * 16;
    const int off0 = swz(row, half * 2) >> 1;
    const int off1 = swz(row, half * 2 + 1) >> 1;
    *(bf16x8*)(Ah + off0) = *(const bf16x8*)(Ahs + base);
    *(bf16x8*)(Ah + off1) = *(const bf16x8*)(Ahs + base + 8);
    *(bf16x8*)(Al + off0) = *(const bf16x8*)(Als + base);
    *(bf16x8*)(Al + off1) = *(const bf16x8*)(Als + base + 8);
    *(bf16x8*)(Bh + off0) = *(const bf16x8*)(Bhs + base);
    *(bf16x8*)(Bh + off1) = *(const bf16x8*)(Bhs + base + 8);
    *(bf16x8*)(Bl + off0) = *(const bf16x8*)(Bls + base);
    *(bf16x8*)(Bl + off1) = *(const bf16x8*)(Bls + base + 8);
}

// one K-step of MFMAs: wave wv covers rows wv*32..+31, all 128 cols
__device__ __forceinline__ void mm_compute(int t, const short* Ah, const short* Al,
                                           const short* Bh, const short* Bl,
                                           f32x4 acc[2][8])
{
    const int lane = t & 63, wv = t >> 6;
    bf16x8 ah[2], al[2];
#pragma unroll
    for (int r = 0; r < 2; ++r) {
        const int rowA = wv * 32 + r * 16 + (lane & 15);
        const int off  = swz(rowA, lane >> 4) >> 1;
        ah[r] = *(const bf16x8*)(Ah + off);
        al[r] = *(const bf16x8*)(Al + off);
    }
#pragma unroll
    for (int c = 0; c < 8; ++c) {
        const int rowB = c * 16 + (lane & 15);
        const int off  = swz(rowB, lane >> 4) >> 1;
        const bf16x8 bh = *(const bf16x8*)(Bh + off);
        const bf16x8 bl = *(const bf16x8*)(Bl + off);
#pragma unroll
        for (int r = 0; r < 2; ++r) {
            acc[r][c] = __builtin_amdgcn_mfma_f32_16x16x32_bf16(ah[r], bh, acc[r][c], 0, 0, 0);
            acc[r][c] = __builtin_amdgcn_mfma_f32_16x16x32_bf16(ah[r], bl, acc[r][c], 0, 0, 0);
            acc[r][c] = __builtin_amdgcn_mfma_f32_16x16x32_bf16(al[r], bh, acc[r][c], 0, 0, 0);
        }
    }
}

// K0: segment offsets
__global__ void seg_kernel(const int* __restrict__ batch, int* __restrict__ seg) {
    int b = blockIdx.x * blockDim.x + threadIdx.x;
    if (b > B_GR) return;
    int lo = 0, hi = N_NODES;
    while (lo < hi) {
        int mid = (lo + hi) >> 1;
        if (batch[mid] < b) lo = mid + 1; else hi = mid;
    }
    seg[b] = lo;
}

// K1: gate GEMM (MFMA), all 4 heads per block -> scores[N][4]
__launch_bounds__(256, 2)
__global__ void gate_kernel(const ushort* __restrict__ xh, const ushort* __restrict__ xl,
                            const ushort* __restrict__ wh, const ushort* __restrict__ wl,
                            const float* __restrict__ b1,
                            const float* __restrict__ w2,
                            const float* __restrict__ b2,
                            float* __restrict__ scores)
{
    __shared__ short Ah[4096], Al[4096], Bh[4096], Bl[4096];
    const int m0 = blockIdx.x * BM, t = threadIdx.x;
    const int lane = t & 63, wv = t >> 6;
    const ushort* Ahs = xh + (long)m0 * KP;
    const ushort* Als = xl + (long)m0 * KP;

    for (int k = 0; k < K_POOL; ++k) {
        const ushort* Bhs = wh + k * H_DIM * KP;
        const ushort* Bls = wl + k * H_DIM * KP;

        f32x4 acc[2][8];
        const f32x4 z = {0.f, 0.f, 0.f, 0.f};
#pragma unroll
        for (int r = 0; r < 2; ++r)
#pragma unroll
            for (int c = 0; c < 8; ++c) acc[r][c] = z;

        for (int ks = 0; ks < KSTEPS; ++ks) {
            __syncthreads();
            mm_stage(Ahs, Als, Bhs, Bls, ks * BK, t, Ah, Al, Bh, Bl);
            __syncthreads();
            mm_compute(t, Ah, Al, Bh, Bl, acc);
        }

        float b1v[8], w2v[8];
#pragma unroll
        for (int c = 0; c < 8; ++c) {
            const int col = c * 16 + (lane & 15);
            b1v[c] = b1[k * H_DIM + col];
            w2v[c] = w2[k * H_DIM + col];
        }
        const float b2v = b2[k];
#pragma unroll
        for (int r = 0; r < 2; ++r)
#pragma unroll
            for (int q = 0; q < 4; ++q) {
                float s = 0.f;
#pragma unroll
                for (int c = 0; c < 8; ++c)
                    s = fmaf(fmaxf(acc[r][c][q] + b1v[c], 0.f), w2v[c], s);
                s += __shfl_xor(s, 1); s += __shfl_xor(s, 2);
                s += __shfl_xor(s, 4); s += __shfl_xor(s, 8);
                if ((lane & 15) == 0) {
                    const int m = m0 + wv * 32 + r * 16 + (lane >> 4) * 4 + q;
                    if (m < N_NODES) scores[m * 4 + k] = s + b2v;
                }
            }
    }
}

// K2: per-graph softmax stats + zero pooled
__launch_bounds__(256)
__global__ void stats_kernel(const float* __restrict__ scores,
                             const int* __restrict__ seg,
                             float* __restrict__ maxv,
                             float* __restrict__ denom,
                             float* __restrict__ pooled)
{
    const int g = blockIdx.x;
    const int t = threadIdx.x;
    const int s = seg[g], e = seg[g + 1];
    const float4* sc4 = (const float4*)scores;

    float mx[4] = {-INFINITY, -INFINITY, -INFINITY, -INFINITY};
    for (int n = s + t; n < e; n += 256) {
        float4 v = sc4[n];
        mx[0] = fmaxf(mx[0], v.x); mx[1] = fmaxf(mx[1], v.y);
        mx[2] = fmaxf(mx[2], v.z); mx[3] = fmaxf(mx[3], v.w);
    }
#pragma unroll
    for (int c = 0; c < 4; ++c)
        for (int off = 32; off; off >>= 1)
            mx[c] = fmaxf(mx[c], __shfl_down(mx[c], off));

    __shared__ float redbuf[4][4];
    __shared__ float bmax[4];
    const int wid = t >> 6, lane = t & 63;
    if (lane == 0)
#pragma unroll
        for (int c = 0; c < 4; ++c) redbuf[wid][c] = mx[c];
    __syncthreads();
    if (t == 0)
#pragma unroll
        for (int c = 0; c < 4; ++c) {
            float m = redbuf[0][c];
            m = fmaxf(m, redbuf[1][c]); m = fmaxf(m, redbuf[2][c]); m = fmaxf(m, redbuf[3][c]);
            bmax[c] = m;
        }
    __syncthreads();
    const float m0v = bmax[0], m1v = bmax[1], m2v = bmax[2], m3v = bmax[3];

    float sm[4] = {0.f, 0.f, 0.f, 0.f};
    for (int n = s + t; n < e; n += 256) {
        float4 v = sc4[n];
        sm[0] += expf(v.x - m0v); sm[1] += expf(v.y - m1v);
        sm[2] += expf(v.z - m2v); sm[3] += expf(v.w - m3v);
    }
#pragma unroll
    for (int c = 0; c < 4; ++c)
        for (int off = 32; off; off >>= 1)
            sm[c] += __shfl_down(sm[c], off);
    __syncthreads();
    if (lane == 0)
#pragma unroll
        for (int c = 0; c < 4; ++c) redbuf[wid][c] = sm[c];
    __syncthreads();
    if (t == 0)
#pragma unroll
        for (int c = 0; c < 4; ++c) {
            maxv[g * 4 + c]  = bmax[c];
            denom[g * 4 + c] = redbuf[0][c] + redbuf[1][c] + redbuf[2][c] + redbuf[3][c] + EPSF;
        }
    pooled[g * 512 + t]       = 0.f;
    pooled[g * 512 + 256 + t] = 0.f;
}

// K3: nn GEMM (MFMA), all 4 heads per block, gated accumulation -> pooled[B][4][128]
__launch_bounds__(256, 2)
__global__ void pool_kernel(const ushort* __restrict__ xh, const ushort* __restrict__ xl,
                            const ushort* __restrict__ wh, const ushort* __restrict__ wl,
                            const int* __restrict__ batch,
                            const float* __restrict__ b1,
                            const float* __restrict__ scores,
                            const float* __restrict__ maxv,
                            const float* __restrict__ denom,
                            float* __restrict__ pooled)
{
    __shared__ short Ah[4096], Al[4096], Bh[4096], Bl[4096];
    __shared__ float lds_pool[GMAX][K_POOL][H_DIM];   // 8 KB
    const int m0 = blockIdx.x * BM, t = threadIdx.x;
    const int lane = t & 63, wv = t >> 6;
    const ushort* Ahs = xh + (long)m0 * KP;
    const ushort* Als = xl + (long)m0 * KP;

    for (int idx = t; idx < GMAX * K_POOL * H_DIM; idx += 256)
        ((float*)lds_pool)[idx] = 0.f;

    const int gfirst0 = batch[m0];

    for (int k = 0; k < K_POOL; ++k) {
        const ushort* Bhs = wh + k * H_DIM * KP;
        const ushort* Bls = wl + k * H_DIM * KP;

        f32x4 acc[2][8];
        const f32x4 z = {0.f, 0.f, 0.f, 0.f};
#pragma unroll
        for (int r = 0; r < 2; ++r)
#pragma unroll
            for (int c = 0; c < 8; ++c) acc[r][c] = z;

        for (int ks = 0; ks < KSTEPS; ++ks) {
            __syncthreads();
            mm_stage(Ahs, Als, Bhs, Bls, ks * BK, t, Ah, Al, Bh, Bl);
            __syncthreads();
            mm_compute(t, Ah, Al, Bh, Bl, acc);
        }

        float b1v[8];
#pragma unroll
        for (int c = 0; c < 8; ++c)
            b1v[c] = b1[k * H_DIM + c * 16 + (lane & 15)];

#pragma unroll
        for (int r = 0; r < 2; ++r) {
            const int mrow = m0 + wv * 32 + r * 16;
            if (mrow >= N_NODES) continue;                       // wave-uniform
            const int mhi   = (mrow + 15 < N_NODES) ? mrow + 15 : N_NODES - 1;
            const int ga    = batch[mrow];
            const bool unif = (batch[mhi] == ga) && (mrow + 15 < N_NODES);
            if (unif) {
                const float mxv = maxv[ga * 4 + k];
                const float den = denom[ga * 4 + k];
                float gates[4];
#pragma unroll
                for (int q = 0; q < 4; ++q) {
                    const int m = mrow + (lane >> 4) * 4 + q;
                    gates[q] = expf(scores[m * 4 + k] - mxv) / den;
                }
                const int lg = ga - gfirst0;
#pragma unroll
                for (int c = 0; c < 8; ++c) {
                    float p = 0.f;
#pragma unroll
                    for (int q = 0; q < 4; ++q)
                        p = fmaf(gates[q], fmaxf(acc[r][c][q] + b1v[c], 0.f), p);
                    p += __shfl_xor(p, 16);
                    p += __shfl_xor(p, 32);
                    if (lane < 16) {
                        if (lg < GMAX) atomicAdd(&lds_pool[lg][k][c * 16 + lane], p);
                        else atomicAdd(&pooled[(ga * K_POOL + k) * H_DIM + c * 16 + lane], p);
                    }
                }
            } else {
#pragma unroll
                for (int q = 0; q < 4; ++q) {
                    const int m = mrow + (lane >> 4) * 4 + q;
                    const bool val = m < N_NODES;
                    int g = ga; float gate = 0.f;
                    if (val) {
                        g = batch[m];
                        gate = expf(scores[m * 4 + k] - maxv[g * 4 + k]) / denom[g * 4 + k];
                    }
                    const int lg = g - gfirst0;
#pragma unroll
                    for (int c = 0; c < 8; ++c) {
                        const float v = gate * fmaxf(acc[r][c][q] + b1v[c], 0.f);
                        if (val && v != 0.f) {
                            if (lg < GMAX) atomicAdd(&lds_pool[lg][k][c * 16 + (lane & 15)], v);
                            else atomicAdd(&pooled[(g * K_POOL + k) * H_DIM + c * 16 + (lane & 15)], v);
                        }
                    }
                }
            }
        }
    }

    __syncthreads();
    {
        const int mlast = (m0 + BM - 1 < N_NODES) ? m0 + BM - 1 : N_NODES - 1;
        int span = batch[mlast] - gfirst0 + 1;
        if (span > GMAX) span = GMAX;
        for (int idx = t; idx < span * K_POOL * H_DIM; idx += 256) {
            const float v = ((const float*)lds_pool)[idx];
            if (v != 0.f) {
                const int lg  = idx >> 9;           // /512
                const int rem = idx & 511;
                atomicAdd(&pooled[(gfirst0 + lg) * 512 + rem], v);
            }
        }
    }
}

// K4: out[g] = [ (pooled@nn_w2 + gs*nn_b2).flatten() | 7 scalars ]
__launch_bounds__(128)
__global__ void out_kernel(const float* __restrict__ pooled,
                           const float* __restrict__ w2,
                           const float* __restrict__ b2,
                           const float* __restrict__ denom,
                           const float* __restrict__ s0, const float* __restrict__ s1,
                           const float* __restrict__ s2, const float* __restrict__ s3,
                           const float* __restrict__ s4, const float* __restrict__ s5,
                           const float* __restrict__ s6,
                           float* __restrict__ out)
{
    const int g = blockIdx.x;
    const int t = threadIdx.x;
    __shared__ float ps[H_DIM];
    float* orow = out + g * OUT_W;

    for (int k = 0; k < K_POOL; ++k) {
        __syncthreads();
        ps[t] = pooled[(g * K_POOL + k) * H_DIM + t];
        __syncthreads();
        const float den = denom[g * 4 + k];
        const float gs  = (den - EPSF) / den;
        float a = b2[k * H_DIM + t] * gs;
        const float* wkt = w2 + (k * H_DIM) * H_DIM + t;
#pragma unroll 4
        for (int h = 0; h < H_DIM; ++h)
            a = fmaf(ps[h], wkt[h * H_DIM], a);
        orow[k * H_DIM + t] = a;
    }
    if (t < 7) {
        const float* sp;
        switch (t) {
            case 0: sp = s0; break; case 1: sp = s1; break; case 2: sp = s2; break;
            case 3: sp = s3; break; case 4: sp = s4; break; case 5: sp = s5; break;
            default: sp = s6; break;
        }
        orow[K_POOL * H_DIM + t] = sp[g];
    }
}

extern "C" void kernel_launch(void* const* d_in, const int* in_sizes, int n_in,
                              void* d_out, int out_size, void* d_ws, size_t ws_size,
                              hipStream_t stream) {
    const float* x     = (const float*)d_in[0];
    const int*   batch = (const int*)d_in[1];
    const float* n_nodes = (const float*)d_in[2];
    const float* Omegas  = (const float*)d_in[3];
    const float* Phis    = (const float*)d_in[4];
    const float* Lambdas = (const float*)d_in[5];
    const float* Omn     = (const float*)d_in[6];
    const float* Phn     = (const float*)d_in[7];
    const float* Lan     = (const float*)d_in[8];
    const float* gw1 = (const float*)d_in[9];
    const float* gb1 = (const float*)d_in[10];
    const float* gw2 = (const float*)d_in[11];
    const float* gb2 = (const float*)d_in[12];
    const float* nw1 = (const float*)d_in[13];
    const float* nb1 = (const float*)d_in[14];
    const float* nw2 = (const float*)d_in[15];
    const float* nb2 = (const float*)d_in[16];

    char* ws = (char*)d_ws;
    ushort* xh  = (ushort*)(ws + OFF_XH);
    ushort* xl  = (ushort*)(ws + OFF_XL);
    ushort* whg = (ushort*)(ws + OFF_WHG);
    ushort* wlg = (ushort*)(ws + OFF_WLG);
    ushort* whn = (ushort*)(ws + OFF_WHN);
    ushort* wln = (ushort*)(ws + OFF_WLN);
    float* scores = (float*)(ws + OFF_SCORES);
    int*   seg    = (int*)(ws + OFF_SEG);
    float* maxv   = (float*)(ws + OFF_MAX);
    float* denom  = (float*)(ws + OFF_DEN);
    float* pooled = (float*)(ws + OFF_POOL);
    float* out    = (float*)d_out;

    // precompute: bf16 hi/lo splits + seg offsets
    cvt_x_kernel<<<(N_PAD * KP / 4 + 255) / 256, 256, 0, stream>>>(x, xh, xl);
    dim3 wgrid((K_POOL * H_DIM * KP + 255) / 256, 2);
    cvt_w_kernel<<<wgrid, 256, 0, stream>>>(gw1, nw1, whg, wlg, whn, wln);
    seg_kernel<<<2, 256, 0, stream>>>(batch, seg);

    gate_kernel<<<NBLK, 256, 0, stream>>>(xh, xl, whg, wlg, gb1, gw2, gb2, scores);
    stats_kernel<<<B_GR, 256, 0, stream>>>(scores, seg, maxv, denom, pooled);
    pool_kernel<<<NBLK, 256, 0, stream>>>(xh, xl, whn, wln, batch, nb1,
                                          scores, maxv, denom, pooled);
    out_kernel<<<B_GR, 128, 0, stream>>>(pooled, nw2, nb2, denom,
                                         n_nodes, Omegas, Phis, Lambdas, Omn, Phn, Lan, out);
}

// Round 9
// 623.661 us; speedup vs baseline: 2.1352x; 1.1341x over previous
//
#include <hip/hip_runtime.h>
#include <math.h>

// ---- problem constants ----
#define N_NODES 250000
#define F_DIM   134
#define H_DIM   128
#define K_POOL  4
#define B_GR    256
#define EPSF    1e-16f
#define OUT_W   (K_POOL * H_DIM + 7)   // 519

// ---- tiling ----
#define BM      128
#define BK      32
#define KSTEPS  5                           // K padded 134 -> 160
#define GMAX    4
#define NBLK    ((N_NODES + BM - 1) / BM)   // 1954
#define TILE_USH 4096                       // ushorts per 8KB tile (128 x 32)

// ---- workspace layout (bytes) ----
#define SZ_XT      (NBLK * KSTEPS * TILE_USH * 2)      // 80,035,840
#define SZ_WT      (K_POOL * KSTEPS * TILE_USH * 2)    // 163,840
#define OFF_XH     0
#define OFF_XL     (OFF_XH + SZ_XT)
#define OFF_WHG    (OFF_XL + SZ_XT)
#define OFF_WLG    (OFF_WHG + SZ_WT)
#define OFF_WHN    (OFF_WLG + SZ_WT)
#define OFF_WLN    (OFF_WHN + SZ_WT)
#define OFF_SCORES (OFF_WLN + SZ_WT)
#define OFF_SEG    (OFF_SCORES + N_NODES * 16)
#define OFF_MAX    (OFF_SEG + 2048)
#define OFF_DEN    (OFF_MAX + 4096)
#define OFF_POOL   (OFF_DEN + 4096)

typedef __attribute__((ext_vector_type(8))) short bf16x8;
typedef __attribute__((ext_vector_type(4))) float f32x4;

__device__ __forceinline__ ushort f2bf(float f) {
    union { float f; unsigned u; } v; v.f = f;
    const unsigned u = v.u;
    return (ushort)((u + 0x7FFFu + ((u >> 16) & 1u)) >> 16);   // RTNE
}
__device__ __forceinline__ float bf2f(ushort h) {
    union { unsigned u; float f; } v; v.u = ((unsigned)h) << 16; return v.f;
}
// XOR swizzle (bijective): byte offset of (row, kg) within an 8KB tile.
// Applied BOTH when pre-swizzling the global tiles (cvt kernels) and on the
// LDS fragment reads (mm_compute); global_load_lds copies linearly (rule 21).
__device__ __forceinline__ int swz(int row, int kg) {
    return ((row << 6) + (kg << 4)) ^ ((row & 7) << 4);
}

// async 16B/lane global->LDS copy (wave-uniform LDS base + lane*16)
__device__ __forceinline__ void gld16(const ushort* g, ushort* l) {
    __builtin_amdgcn_global_load_lds(
        (const __attribute__((address_space(1))) unsigned*)g,
        (__attribute__((address_space(3))) unsigned*)l, 16, 0, 0);
}

// ---- P0: x -> hi/lo bf16 pre-swizzled tiles [NBLK][KSTEPS][8KB] ----
__launch_bounds__(256)
__global__ void cvt_x_kernel(const float* __restrict__ x,
                             ushort* __restrict__ xh, ushort* __restrict__ xl)
{
    const int u = blockIdx.x * 256 + threadIdx.x;   // over NBLK*KSTEPS*512
    if (u >= NBLK * KSTEPS * 512) return;
    const int tile = u >> 9;
    const int e    = u & 511;
    const int row  = e >> 2, kg = e & 3;
    const int blk  = tile / KSTEPS, ks = tile - blk * KSTEPS;
    const int node = blk * BM + row;
    const int col0 = ks * BK + kg * 8;

    float v[8];
#pragma unroll
    for (int j = 0; j < 8; ++j) v[j] = 0.f;
    if (node < N_NODES) {
        const float* xr = x + (long)node * F_DIM + col0;
        if (col0 + 8 <= F_DIM) {
#pragma unroll
            for (int j = 0; j < 4; ++j) {
                float2 a = *(const float2*)(xr + 2 * j);
                v[2 * j] = a.x; v[2 * j + 1] = a.y;
            }
        } else if (col0 < F_DIM) {   // col0 == 128: cols 128..133 valid
#pragma unroll
            for (int j = 0; j < 3; ++j) {
                float2 a = *(const float2*)(xr + 2 * j);
                v[2 * j] = a.x; v[2 * j + 1] = a.y;
            }
        }
    }
    bf16x8 h, l;
#pragma unroll
    for (int j = 0; j < 8; ++j) {
        const ushort hh = f2bf(v[j]);
        h[j] = (short)hh;
        l[j] = (short)f2bf(v[j] - bf2f(hh));
    }
    const long dst = (long)tile * TILE_USH + (swz(row, kg) >> 1);
    *(bf16x8*)(xh + dst) = h;
    *(bf16x8*)(xl + dst) = l;
}

// ---- P1: w1 -> transposed hi/lo pre-swizzled tiles [head][ks][8KB] ----
__launch_bounds__(256)
__global__ void cvt_w_kernel(const float* __restrict__ wg, const float* __restrict__ wn,
                             ushort* __restrict__ whg, ushort* __restrict__ wlg,
                             ushort* __restrict__ whn, ushort* __restrict__ wln)
{
    const int u = blockIdx.x * 256 + threadIdx.x;   // over K_POOL*KSTEPS*512
    if (u >= K_POOL * KSTEPS * 512) return;
    const int tile = u >> 9;
    const int e    = u & 511;
    const int col  = e >> 2, kg = e & 3;
    const int head = tile / KSTEPS, ks = tile - head * KSTEPS;
    const int k0   = ks * BK + kg * 8;
    const float* src = blockIdx.y ? wn : wg;
    const float* sp  = src + ((long)head * F_DIM) * H_DIM + col;

    float v[8];
#pragma unroll
    for (int j = 0; j < 8; ++j)
        v[j] = (k0 + j < F_DIM) ? sp[(k0 + j) * H_DIM] : 0.f;
    bf16x8 h, l;
#pragma unroll
    for (int j = 0; j < 8; ++j) {
        const ushort hh = f2bf(v[j]);
        h[j] = (short)hh;
        l[j] = (short)f2bf(v[j] - bf2f(hh));
    }
    const long dst = (long)tile * TILE_USH + (swz(col, kg) >> 1);
    if (blockIdx.y) { *(bf16x8*)(whn + dst) = h; *(bf16x8*)(wln + dst) = l; }
    else            { *(bf16x8*)(whg + dst) = h; *(bf16x8*)(wlg + dst) = l; }
}

// ---- stage one K-step: 32KB via 8 async 1KB wave-streams ----
__device__ __forceinline__ void stage_ks(const ushort* __restrict__ Ath,
                                         const ushort* __restrict__ Atl,
                                         const ushort* __restrict__ Bth,
                                         const ushort* __restrict__ Btl,
                                         ushort* lds, int t)
{
    const int wv  = t >> 6;
    const int wo  = wv * 1024;          // ushort offset of wave's 2KB chunk
    const int lo8 = (t & 63) * 8;       // lane's 16B within 1KB
    gld16(Ath + wo + lo8,       lds + wo);
    gld16(Ath + wo + 512 + lo8, lds + wo + 512);
    gld16(Atl + wo + lo8,       lds + 4096 + wo);
    gld16(Atl + wo + 512 + lo8, lds + 4096 + wo + 512);
    gld16(Bth + wo + lo8,       lds + 8192 + wo);
    gld16(Bth + wo + 512 + lo8, lds + 8192 + wo + 512);
    gld16(Btl + wo + lo8,       lds + 12288 + wo);
    gld16(Btl + wo + 512 + lo8, lds + 12288 + wo + 512);
}

// one K-step of MFMAs: wave wv covers rows wv*32..+31, all 128 cols
__device__ __forceinline__ void mm_compute(int t, const ushort* Ah, const ushort* Al,
                                           const ushort* Bh, const ushort* Bl,
                                           f32x4 acc[2][8])
{
    const int lane = t & 63, wv = t >> 6;
    bf16x8 ah[2], al[2];
#pragma unroll
    for (int r = 0; r < 2; ++r) {
        const int rowA = wv * 32 + r * 16 + (lane & 15);
        const int off  = swz(rowA, lane >> 4) >> 1;
        ah[r] = *(const bf16x8*)(Ah + off);
        al[r] = *(const bf16x8*)(Al + off);
    }
#pragma unroll
    for (int c = 0; c < 8; ++c) {
        const int rowB = c * 16 + (lane & 15);
        const int off  = swz(rowB, lane >> 4) >> 1;
        const bf16x8 bh = *(const bf16x8*)(Bh + off);
        const bf16x8 bl = *(const bf16x8*)(Bl + off);
#pragma unroll
        for (int r = 0; r < 2; ++r) {
            acc[r][c] = __builtin_amdgcn_mfma_f32_16x16x32_bf16(ah[r], bh, acc[r][c], 0, 0, 0);
            acc[r][c] = __builtin_amdgcn_mfma_f32_16x16x32_bf16(ah[r], bl, acc[r][c], 0, 0, 0);
            acc[r][c] = __builtin_amdgcn_mfma_f32_16x16x32_bf16(al[r], bh, acc[r][c], 0, 0, 0);
        }
    }
}

// K0: segment offsets
__global__ void seg_kernel(const int* __restrict__ batch, int* __restrict__ seg) {
    int b = blockIdx.x * blockDim.x + threadIdx.x;
    if (b > B_GR) return;
    int lo = 0, hi = N_NODES;
    while (lo < hi) {
        int mid = (lo + hi) >> 1;
        if (batch[mid] < b) lo = mid + 1; else hi = mid;
    }
    seg[b] = lo;
}

// K1: gate GEMM (MFMA), all 4 heads per block -> scores[N][4]
__launch_bounds__(256, 2)
__global__ void gate_kernel(const ushort* __restrict__ xh, const ushort* __restrict__ xl,
                            const ushort* __restrict__ wh, const ushort* __restrict__ wl,
                            const float* __restrict__ b1,
                            const float* __restrict__ w2,
                            const float* __restrict__ b2,
                            float* __restrict__ scores)
{
    __shared__ ushort slds[16384];   // 32 KB: Ah|Al|Bh|Bl
    const int m0 = blockIdx.x * BM, t = threadIdx.x;
    const int lane = t & 63, wv = t >> 6;
    const ushort* Ath = xh + (long)blockIdx.x * KSTEPS * TILE_USH;
    const ushort* Atl = xl + (long)blockIdx.x * KSTEPS * TILE_USH;

    for (int k = 0; k < K_POOL; ++k) {
        const ushort* Bth = wh + (long)k * KSTEPS * TILE_USH;
        const ushort* Btl = wl + (long)k * KSTEPS * TILE_USH;

        f32x4 acc[2][8];
        const f32x4 z = {0.f, 0.f, 0.f, 0.f};
#pragma unroll
        for (int r = 0; r < 2; ++r)
#pragma unroll
            for (int c = 0; c < 8; ++c) acc[r][c] = z;

        for (int ks = 0; ks < KSTEPS; ++ks) {
            __syncthreads();
            stage_ks(Ath + ks * TILE_USH, Atl + ks * TILE_USH,
                     Bth + ks * TILE_USH, Btl + ks * TILE_USH, slds, t);
            __syncthreads();
            mm_compute(t, slds, slds + 4096, slds + 8192, slds + 12288, acc);
        }

        float b1v[8], w2v[8];
#pragma unroll
        for (int c = 0; c < 8; ++c) {
            const int col = c * 16 + (lane & 15);
            b1v[c] = b1[k * H_DIM + col];
            w2v[c] = w2[k * H_DIM + col];
        }
        const float b2v = b2[k];
#pragma unroll
        for (int r = 0; r < 2; ++r)
#pragma unroll
            for (int q = 0; q < 4; ++q) {
                float s = 0.f;
#pragma unroll
                for (int c = 0; c < 8; ++c)
                    s = fmaf(fmaxf(acc[r][c][q] + b1v[c], 0.f), w2v[c], s);
                s += __shfl_xor(s, 1); s += __shfl_xor(s, 2);
                s += __shfl_xor(s, 4); s += __shfl_xor(s, 8);
                if ((lane & 15) == 0) {
                    const int m = m0 + wv * 32 + r * 16 + (lane >> 4) * 4 + q;
                    if (m < N_NODES) scores[m * 4 + k] = s + b2v;
                }
            }
    }
}

// K2: per-graph softmax stats + zero pooled
__launch_bounds__(256)
__global__ void stats_kernel(const float* __restrict__ scores,
                             const int* __restrict__ seg,
                             float* __restrict__ maxv,
                             float* __restrict__ denom,
                             float* __restrict__ pooled)
{
    const int g = blockIdx.x;
    const int t = threadIdx.x;
    const int s = seg[g], e = seg[g + 1];
    const float4* sc4 = (const float4*)scores;

    float mx[4] = {-INFINITY, -INFINITY, -INFINITY, -INFINITY};
    for (int n = s + t; n < e; n += 256) {
        float4 v = sc4[n];
        mx[0] = fmaxf(mx[0], v.x); mx[1] = fmaxf(mx[1], v.y);
        mx[2] = fmaxf(mx[2], v.z); mx[3] = fmaxf(mx[3], v.w);
    }
#pragma unroll
    for (int c = 0; c < 4; ++c)
        for (int off = 32; off; off >>= 1)
            mx[c] = fmaxf(mx[c], __shfl_down(mx[c], off));

    __shared__ float redbuf[4][4];
    __shared__ float bmax[4];
    const int wid = t >> 6, lane = t & 63;
    if (lane == 0)
#pragma unroll
        for (int c = 0; c < 4; ++c) redbuf[wid][c] = mx[c];
    __syncthreads();
    if (t == 0)
#pragma unroll
        for (int c = 0; c < 4; ++c) {
            float m = redbuf[0][c];
            m = fmaxf(m, redbuf[1][c]); m = fmaxf(m, redbuf[2][c]); m = fmaxf(m, redbuf[3][c]);
            bmax[c] = m;
        }
    __syncthreads();
    const float m0v = bmax[0], m1v = bmax[1], m2v = bmax[2], m3v = bmax[3];

    float sm[4] = {0.f, 0.f, 0.f, 0.f};
    for (int n = s + t; n < e; n += 256) {
        float4 v = sc4[n];
        sm[0] += expf(v.x - m0v); sm[1] += expf(v.y - m1v);
        sm[2] += expf(v.z - m2v); sm[3] += expf(v.w - m3v);
    }
#pragma unroll
    for (int c = 0; c < 4; ++c)
        for (int off = 32; off; off >>= 1)
            sm[c] += __shfl_down(sm[c], off);
    __syncthreads();
    if (lane == 0)
#pragma unroll
        for (int c = 0; c < 4; ++c) redbuf[wid][c] = sm[c];
    __syncthreads();
    if (t == 0)
#pragma unroll
        for (int c = 0; c < 4; ++c) {
            maxv[g * 4 + c]  = bmax[c];
            denom[g * 4 + c] = redbuf[0][c] + redbuf[1][c] + redbuf[2][c] + redbuf[3][c] + EPSF;
        }
    pooled[g * 512 + t]       = 0.f;
    pooled[g * 512 + 256 + t] = 0.f;
}

// K3: nn GEMM (MFMA), all 4 heads per block, gated accumulation -> pooled[B][4][128]
__launch_bounds__(256, 2)
__global__ void pool_kernel(const ushort* __restrict__ xh, const ushort* __restrict__ xl,
                            const ushort* __restrict__ wh, const ushort* __restrict__ wl,
                            const int* __restrict__ batch,
                            const float* __restrict__ b1,
                            const float* __restrict__ scores,
                            const float* __restrict__ maxv,
                            const float* __restrict__ denom,
                            float* __restrict__ pooled)
{
    __shared__ ushort slds[16384];                    // 32 KB staging
    __shared__ float lds_pool[GMAX][K_POOL][H_DIM];   // 8 KB
    const int m0 = blockIdx.x * BM, t = threadIdx.x;
    const int lane = t & 63, wv = t >> 6;
    const ushort* Ath = xh + (long)blockIdx.x * KSTEPS * TILE_USH;
    const ushort* Atl = xl + (long)blockIdx.x * KSTEPS * TILE_USH;

    for (int idx = t; idx < GMAX * K_POOL * H_DIM; idx += 256)
        ((float*)lds_pool)[idx] = 0.f;

    const int gfirst0 = batch[m0];

    for (int k = 0; k < K_POOL; ++k) {
        const ushort* Bth = wh + (long)k * KSTEPS * TILE_USH;
        const ushort* Btl = wl + (long)k * KSTEPS * TILE_USH;

        f32x4 acc[2][8];
        const f32x4 z = {0.f, 0.f, 0.f, 0.f};
#pragma unroll
        for (int r = 0; r < 2; ++r)
#pragma unroll
            for (int c = 0; c < 8; ++c) acc[r][c] = z;

        for (int ks = 0; ks < KSTEPS; ++ks) {
            __syncthreads();
            stage_ks(Ath + ks * TILE_USH, Atl + ks * TILE_USH,
                     Bth + ks * TILE_USH, Btl + ks * TILE_USH, slds, t);
            __syncthreads();
            mm_compute(t, slds, slds + 4096, slds + 8192, slds + 12288, acc);
        }

        float b1v[8];
#pragma unroll
        for (int c = 0; c < 8; ++c)
            b1v[c] = b1[k * H_DIM + c * 16 + (lane & 15)];

#pragma unroll
        for (int r = 0; r < 2; ++r) {
            const int mrow = m0 + wv * 32 + r * 16;
            if (mrow >= N_NODES) continue;                       // wave-uniform
            const int mhi   = (mrow + 15 < N_NODES) ? mrow + 15 : N_NODES - 1;
            const int ga    = batch[mrow];
            const bool unif = (batch[mhi] == ga) && (mrow + 15 < N_NODES);
            if (unif) {
                const float mxv = maxv[ga * 4 + k];
                const float den = denom[ga * 4 + k];
                float gates[4];
#pragma unroll
                for (int q = 0; q < 4; ++q) {
                    const int m = mrow + (lane >> 4) * 4 + q;
                    gates[q] = expf(scores[m * 4 + k] - mxv) / den;
                }
                const int lg = ga - gfirst0;
#pragma unroll
                for (int c = 0; c < 8; ++c) {
                    float p = 0.f;
#pragma unroll
                    for (int q = 0; q < 4; ++q)
                        p = fmaf(gates[q], fmaxf(acc[r][c][q] + b1v[c], 0.f), p);
                    p += __shfl_xor(p, 16);
                    p += __shfl_xor(p, 32);
                    if (lane < 16) {
                        if (lg < GMAX) atomicAdd(&lds_pool[lg][k][c * 16 + lane], p);
                        else atomicAdd(&pooled[(ga * K_POOL + k) * H_DIM + c * 16 + lane], p);
                    }
                }
            } else {
#pragma unroll
                for (int q = 0; q < 4; ++q) {
                    const int m = mrow + (lane >> 4) * 4 + q;
                    const bool val = m < N_NODES;
                    int g = ga; float gate = 0.f;
                    if (val) {
                        g = batch[m];
                        gate = expf(scores[m * 4 + k] - maxv[g * 4 + k]) / denom[g * 4 + k];
                    }
                    const int lg = g - gfirst0;
#pragma unroll
                    for (int c = 0; c < 8; ++c) {
                        const float v = gate * fmaxf(acc[r][c][q] + b1v[c], 0.f);
                        if (val && v != 0.f) {
                            if (lg < GMAX) atomicAdd(&lds_pool[lg][k][c * 16 + (lane & 15)], v);
                            else atomicAdd(&pooled[(g * K_POOL + k) * H_DIM + c * 16 + (lane & 15)], v);
                        }
                    }
                }
            }
        }
    }

    __syncthreads();
    {
        const int mlast = (m0 + BM - 1 < N_NODES) ? m0 + BM - 1 : N_NODES - 1;
        int span = batch[mlast] - gfirst0 + 1;
        if (span > GMAX) span = GMAX;
        for (int idx = t; idx < span * K_POOL * H_DIM; idx += 256) {
            const float v = ((const float*)lds_pool)[idx];
            if (v != 0.f) {
                const int lg  = idx >> 9;           // /512
                const int rem = idx & 511;
                atomicAdd(&pooled[(gfirst0 + lg) * 512 + rem], v);
            }
        }
    }
}

// K4: out[g] = [ (pooled@nn_w2 + gs*nn_b2).flatten() | 7 scalars ]
__launch_bounds__(128)
__global__ void out_kernel(const float* __restrict__ pooled,
                           const float* __restrict__ w2,
                           const float* __restrict__ b2,
                           const float* __restrict__ denom,
                           const float* __restrict__ s0, const float* __restrict__ s1,
                           const float* __restrict__ s2, const float* __restrict__ s3,
                           const float* __restrict__ s4, const float* __restrict__ s5,
                           const float* __restrict__ s6,
                           float* __restrict__ out)
{
    const int g = blockIdx.x;
    const int t = threadIdx.x;
    __shared__ float ps[H_DIM];
    float* orow = out + g * OUT_W;

    for (int k = 0; k < K_POOL; ++k) {
        __syncthreads();
        ps[t] = pooled[(g * K_POOL + k) * H_DIM + t];
        __syncthreads();
        const float den = denom[g * 4 + k];
        const float gs  = (den - EPSF) / den;
        float a = b2[k * H_DIM + t] * gs;
        const float* wkt = w2 + (k * H_DIM) * H_DIM + t;
#pragma unroll 4
        for (int h = 0; h < H_DIM; ++h)
            a = fmaf(ps[h], wkt[h * H_DIM], a);
        orow[k * H_DIM + t] = a;
    }
    if (t < 7) {
        const float* sp;
        switch (t) {
            case 0: sp = s0; break; case 1: sp = s1; break; case 2: sp = s2; break;
            case 3: sp = s3; break; case 4: sp = s4; break; case 5: sp = s5; break;
            default: sp = s6; break;
        }
        orow[K_POOL * H_DIM + t] = sp[g];
    }
}

extern "C" void kernel_launch(void* const* d_in, const int* in_sizes, int n_in,
                              void* d_out, int out_size, void* d_ws, size_t ws_size,
                              hipStream_t stream) {
    const float* x     = (const float*)d_in[0];
    const int*   batch = (const int*)d_in[1];
    const float* n_nodes = (const float*)d_in[2];
    const float* Omegas  = (const float*)d_in[3];
    const float* Phis    = (const float*)d_in[4];
    const float* Lambdas = (const float*)d_in[5];
    const float* Omn     = (const float*)d_in[6];
    const float* Phn     = (const float*)d_in[7];
    const float* Lan     = (const float*)d_in[8];
    const float* gw1 = (const float*)d_in[9];
    const float* gb1 = (const float*)d_in[10];
    const float* gw2 = (const float*)d_in[11];
    const float* gb2 = (const float*)d_in[12];
    const float* nw1 = (const float*)d_in[13];
    const float* nb1 = (const float*)d_in[14];
    const float* nw2 = (const float*)d_in[15];
    const float* nb2 = (const float*)d_in[16];

    char* ws = (char*)d_ws;
    ushort* xh  = (ushort*)(ws + OFF_XH);
    ushort* xl  = (ushort*)(ws + OFF_XL);
    ushort* whg = (ushort*)(ws + OFF_WHG);
    ushort* wlg = (ushort*)(ws + OFF_WLG);
    ushort* whn = (ushort*)(ws + OFF_WHN);
    ushort* wln = (ushort*)(ws + OFF_WLN);
    float* scores = (float*)(ws + OFF_SCORES);
    int*   seg    = (int*)(ws + OFF_SEG);
    float* maxv   = (float*)(ws + OFF_MAX);
    float* denom  = (float*)(ws + OFF_DEN);
    float* pooled = (float*)(ws + OFF_POOL);
    float* out    = (float*)d_out;

    // precompute: pre-swizzled bf16 hi/lo tiles + seg offsets
    cvt_x_kernel<<<(NBLK * KSTEPS * 512) / 256, 256, 0, stream>>>(x, xh, xl);
    dim3 wgrid((K_POOL * KSTEPS * 512 + 255) / 256, 2);
    cvt_w_kernel<<<wgrid, 256, 0, stream>>>(gw1, nw1, whg, wlg, whn, wln);
    seg_kernel<<<2, 256, 0, stream>>>(batch, seg);

    gate_kernel<<<NBLK, 256, 0, stream>>>(xh, xl, whg, wlg, gb1, gw2, gb2, scores);
    stats_kernel<<<B_GR, 256, 0, stream>>>(scores, seg, maxv, denom, pooled);
    pool_kernel<<<NBLK, 256, 0, stream>>>(xh, xl, whn, wln, batch, nb1,
                                          scores, maxv, denom, pooled);
    out_kernel<<<B_GR, 128, 0, stream>>>(pooled, nw2, nb2, denom,
                                         n_nodes, Omegas, Phis, Lambdas, Omn, Phn, Lan, out);
}